// Round 1
// baseline (81.795 us; speedup 1.0000x reference)
//
#include <hip/hip_runtime.h>

// Quanvolution: 4096 images * 196 patches = 802816 independent 4-qubit circuit sims.
// One thread per patch. 16 complex amplitudes live in registers (32 VGPRs).
// 8 gate matrices (2 layers x 4 wires) computed once per block into LDS by threads 0..7.

__device__ __forceinline__ float2 cmul(float2 a, float2 b) {
    return make_float2(fmaf(a.x, b.x, -(a.y * b.y)),
                       fmaf(a.x, b.y,   a.y * b.x));
}
__device__ __forceinline__ float2 cfma(float2 a, float2 b, float2 c) {
    // a*b + c
    return make_float2(fmaf(a.x, b.x, fmaf(-a.y, b.y, c.x)),
                       fmaf(a.x, b.y, fmaf( a.y, b.x, c.y)));
}

__global__ __launch_bounds__(256) void quanv_kernel(
        const float* __restrict__ x,       // (4096, 28, 28)
        const float* __restrict__ params,  // (2, 4, 3)
        float* __restrict__ out)           // (4096, 784) = (4096, 196*4) patch-major wire-minor
{
    // ---- per-block gate precompute: U = RX(p2/2) @ RZ(p1/2) @ RY(p0/2) ----
    __shared__ float2 G[8][4];   // gate g = l*4+w ; entries [U00,U01,U10,U11]
    const int t = threadIdx.x;
    if (t < 8) {
        const float* p = params + t * 3;   // (l*4+w)*3 == l*12 + w*3
        float sa, ca, sb, cb, sc, cc;
        __sincosf(0.5f * p[0], &sa, &ca);
        __sincosf(0.5f * p[1], &sb, &cb);
        __sincosf(0.5f * p[2], &sc, &cc);
        // derived analytically; checked vs RY (b=c=0), RZ (a=c=0), RX (a=b=0)
        G[t][0] = make_float2( cc*ca*cb + sc*sa*sb, -cc*ca*sb - sc*sa*cb);
        G[t][1] = make_float2(-cc*sa*cb + sc*ca*sb,  cc*sa*sb - sc*ca*cb);
        G[t][2] = make_float2( cc*sa*cb - sc*ca*sb,  cc*sa*sb - sc*ca*cb);
        G[t][3] = make_float2( sa*sc*sb + cc*ca*cb,  sa*sc*cb + cc*ca*sb);
    }
    __syncthreads();

    const int gid = blockIdx.x * 256 + t;          // patch id: n*196 + r*14 + c
    const int n = gid / 196;
    const int p = gid - n * 196;
    const int r = p / 14;
    const int c = p - r * 14;

    // patch values: [x(2r,2c), x(2r,2c+1), x(2r+1,2c), x(2r+1,2c+1)]
    const float* xb = x + n * 784 + r * 56 + c * 2;   // even element offset -> 8B aligned
    const float2 top = *(const float2*)(xb);
    const float2 bot = *(const float2*)(xb + 28);

    // RY(patch)|0> per wire: v[w] = (cos(p/2), sin(p/2))
    float vc[4], vs[4];
    __sincosf(0.5f * top.x, &vs[0], &vc[0]);
    __sincosf(0.5f * top.y, &vs[1], &vc[1]);
    __sincosf(0.5f * bot.x, &vs[2], &vc[2]);
    __sincosf(0.5f * bot.y, &vs[3], &vc[3]);

    // initial product state (real). idx bit for wire w is (8 >> w).
    float2 s[16];
#pragma unroll
    for (int a = 0; a < 2; ++a)
#pragma unroll
        for (int b = 0; b < 2; ++b)
#pragma unroll
            for (int cc2 = 0; cc2 < 2; ++cc2)
#pragma unroll
                for (int d = 0; d < 2; ++d) {
                    float va = a ? vs[0] : vc[0];
                    float vb = b ? vs[1] : vc[1];
                    float vcx = cc2 ? vs[2] : vc[2];
                    float vd = d ? vs[3] : vc[3];
                    s[a * 8 + b * 4 + cc2 * 2 + d] = make_float2(va * vb * vcx * vd, 0.0f);
                }

#pragma unroll
    for (int l = 0; l < 2; ++l) {
        // single-qubit gates on wires 0..3
#pragma unroll
        for (int w = 0; w < 4; ++w) {
            const int g = l * 4 + w;
            const float2 U00 = G[g][0], U01 = G[g][1], U10 = G[g][2], U11 = G[g][3];
            const int bit = 8 >> w;
#pragma unroll
            for (int i = 0; i < 16; ++i) {
                if (i & bit) continue;
                const float2 x0 = s[i], x1 = s[i | bit];
                s[i]       = cfma(U01, x1, cmul(U00, x0));
                s[i | bit] = cfma(U11, x1, cmul(U10, x0));
            }
        }
        // ring of CNOTs: (0,1),(1,2),(2,3),(3,0) — pure register swaps
#pragma unroll
        for (int k = 0; k < 4; ++k) {
            const int bc = 8 >> k;
            const int bt = 8 >> ((k + 1) & 3);
#pragma unroll
            for (int i = 0; i < 16; ++i) {
                if ((i & bc) && !(i & bt)) {
                    const float2 tmp = s[i];
                    s[i] = s[i | bt];
                    s[i | bt] = tmp;
                }
            }
        }
    }

    // <Z_w> = sum over basis states of |amp|^2 * (+1 if bit clear else -1)
    float e0 = 0.f, e1 = 0.f, e2 = 0.f, e3 = 0.f;
#pragma unroll
    for (int i = 0; i < 16; ++i) {
        const float pr = fmaf(s[i].x, s[i].x, s[i].y * s[i].y);
        e0 += (i & 8) ? -pr : pr;
        e1 += (i & 4) ? -pr : pr;
        e2 += (i & 2) ? -pr : pr;
        e3 += (i & 1) ? -pr : pr;
    }

    *(float4*)(out + gid * 4) = make_float4(e0, e1, e2, e3);
}

extern "C" void kernel_launch(void* const* d_in, const int* in_sizes, int n_in,
                              void* d_out, int out_size, void* d_ws, size_t ws_size,
                              hipStream_t stream) {
    const float* x      = (const float*)d_in[0];   // 4096*28*28
    const float* params = (const float*)d_in[1];   // 2*4*3
    float* out = (float*)d_out;                    // 4096*784

    const int npatch = 4096 * 196;                 // 802816, divisible by 256
    quanv_kernel<<<npatch / 256, 256, 0, stream>>>(x, params, out);
}

// Round 2
// 74.886 us; speedup vs baseline: 1.0923x; 1.0923x over previous
//
#include <hip/hip_runtime.h>

// Quanvolution: 4096 images * 196 patches = 802816 independent 4-qubit circuit sims.
// One thread per patch; 16 complex amplitudes in registers.
// Layer-1 gates are applied to the per-wire 2-vectors BEFORE forming the tensor
// product (product state => per-wire application is exact), cutting ~560 VALU
// instrs to ~128. Layer-2 acts on the entangled state via full butterflies.
// 8 gate matrices precomputed per block into LDS by threads 0..7 (broadcast reads).

__device__ __forceinline__ float2 cmul(float2 a, float2 b) {
    return make_float2(fmaf(a.x, b.x, -(a.y * b.y)),
                       fmaf(a.x, b.y,   a.y * b.x));
}
__device__ __forceinline__ float2 cfma(float2 a, float2 b, float2 c) {
    // a*b + c
    return make_float2(fmaf(a.x, b.x, fmaf(-a.y, b.y, c.x)),
                       fmaf(a.x, b.y, fmaf( a.y, b.x, c.y)));
}

__global__ __launch_bounds__(256) void quanv_kernel(
        const float* __restrict__ x,       // (4096, 28, 28)
        const float* __restrict__ params,  // (2, 4, 3)
        float* __restrict__ out)           // (4096, 196*4) patch-major wire-minor
{
    // ---- per-block gate precompute: U = RX(p2/2) @ RZ(p1/2) @ RY(p0/2) ----
    __shared__ float2 G[8][4];   // gate g = l*4+w ; entries [U00,U01,U10,U11]
    const int t = threadIdx.x;
    if (t < 8) {
        const float* p = params + t * 3;
        const float a = 0.5f * p[0], b = 0.5f * p[1], c = 0.5f * p[2];
        const float sa = __sinf(a), ca = __cosf(a);
        const float sb = __sinf(b), cb = __cosf(b);
        const float sc = __sinf(c), cc = __cosf(c);
        G[t][0] = make_float2( cc*ca*cb + sc*sa*sb, -cc*ca*sb - sc*sa*cb);
        G[t][1] = make_float2(-cc*sa*cb + sc*ca*sb,  cc*sa*sb - sc*ca*cb);
        G[t][2] = make_float2( cc*sa*cb - sc*ca*sb,  cc*sa*sb - sc*ca*cb);
        G[t][3] = make_float2( sa*sc*sb + cc*ca*cb,  sa*sc*cb + cc*ca*sb);
    }
    __syncthreads();

    const int gid = blockIdx.x * 256 + t;          // patch id: n*196 + r*14 + c
    const int n = gid / 196;
    const int p = gid - n * 196;
    const int r = p / 14;
    const int c = p - r * 14;

    // patch values: [x(2r,2c), x(2r,2c+1), x(2r+1,2c), x(2r+1,2c+1)]
    const float* xb = x + n * 784 + r * 56 + c * 2;   // even offset -> 8B aligned
    const float2 top = *(const float2*)(xb);
    const float2 bot = *(const float2*)(xb + 28);

    // RY(patch)|0> per wire: (cos(p/2), sin(p/2)), then layer-1 gate on the wire
    float pv[4] = {0.5f * top.x, 0.5f * top.y, 0.5f * bot.x, 0.5f * bot.y};
    float2 wv[4][2];   // per-wire 2-vector after layer-1 gate (complex)
#pragma unroll
    for (int w = 0; w < 4; ++w) {
        const float cw = __cosf(pv[w]);
        const float sw = __sinf(pv[w]);
        const float2 U00 = G[w][0], U01 = G[w][1], U10 = G[w][2], U11 = G[w][3];
        wv[w][0] = make_float2(fmaf(U01.x, sw, U00.x * cw), fmaf(U01.y, sw, U00.y * cw));
        wv[w][1] = make_float2(fmaf(U11.x, sw, U10.x * cw), fmaf(U11.y, sw, U10.y * cw));
    }

    // tensor product: s[a*8+b*4+c*2+d] = wv0[a]*wv1[b]*wv2[c]*wv3[d]
    float2 ab[4], cd[4];
#pragma unroll
    for (int i = 0; i < 2; ++i)
#pragma unroll
        for (int j = 0; j < 2; ++j) {
            ab[i * 2 + j] = cmul(wv[0][i], wv[1][j]);
            cd[i * 2 + j] = cmul(wv[2][i], wv[3][j]);
        }
    float2 s[16];
#pragma unroll
    for (int hi = 0; hi < 4; ++hi)
#pragma unroll
        for (int lo = 0; lo < 4; ++lo)
            s[hi * 4 + lo] = cmul(ab[hi], cd[lo]);

    // layer-1 CNOT ring: (0,1),(1,2),(2,3),(3,0) — register renames after unroll
#pragma unroll
    for (int k = 0; k < 4; ++k) {
        const int bc = 8 >> k;
        const int bt = 8 >> ((k + 1) & 3);
#pragma unroll
        for (int i = 0; i < 16; ++i)
            if ((i & bc) && !(i & bt)) {
                const float2 tmp = s[i]; s[i] = s[i | bt]; s[i | bt] = tmp;
            }
    }

    // layer-2 single-qubit gates (full-state butterflies)
#pragma unroll
    for (int w = 0; w < 4; ++w) {
        const int g = 4 + w;
        const float2 U00 = G[g][0], U01 = G[g][1], U10 = G[g][2], U11 = G[g][3];
        const int bit = 8 >> w;
#pragma unroll
        for (int i = 0; i < 16; ++i) {
            if (i & bit) continue;
            const float2 x0 = s[i], x1 = s[i | bit];
            s[i]       = cfma(U01, x1, cmul(U00, x0));
            s[i | bit] = cfma(U11, x1, cmul(U10, x0));
        }
    }

    // layer-2 CNOT ring
#pragma unroll
    for (int k = 0; k < 4; ++k) {
        const int bc = 8 >> k;
        const int bt = 8 >> ((k + 1) & 3);
#pragma unroll
        for (int i = 0; i < 16; ++i)
            if ((i & bc) && !(i & bt)) {
                const float2 tmp = s[i]; s[i] = s[i | bt]; s[i | bt] = tmp;
            }
    }

    // <Z_w> via shared partial sums. i = a*8+b*4+c*2+d; wire0=a ... wire3=d
    float pr[16];
#pragma unroll
    for (int i = 0; i < 16; ++i)
        pr[i] = fmaf(s[i].x, s[i].x, s[i].y * s[i].y);

    const float t00 = pr[0] + pr[1] + pr[2]  + pr[3];    // a=0,b=0
    const float t01 = pr[4] + pr[5] + pr[6]  + pr[7];    // a=0,b=1
    const float t10 = pr[8] + pr[9] + pr[10] + pr[11];   // a=1,b=0
    const float t11 = pr[12] + pr[13] + pr[14] + pr[15]; // a=1,b=1
    const float e0 = (t00 + t01) - (t10 + t11);
    const float e1 = (t00 - t01) + (t10 - t11);

    const float u00 = pr[0] + pr[4] + pr[8]  + pr[12];   // c=0,d=0
    const float u01 = pr[1] + pr[5] + pr[9]  + pr[13];   // c=0,d=1
    const float u10 = pr[2] + pr[6] + pr[10] + pr[14];   // c=1,d=0
    const float u11 = pr[3] + pr[7] + pr[11] + pr[15];   // c=1,d=1
    const float e2 = (u00 + u01) - (u10 + u11);
    const float e3 = (u00 - u01) + (u10 - u11);

    *(float4*)(out + gid * 4) = make_float4(e0, e1, e2, e3);
}

extern "C" void kernel_launch(void* const* d_in, const int* in_sizes, int n_in,
                              void* d_out, int out_size, void* d_ws, size_t ws_size,
                              hipStream_t stream) {
    const float* x      = (const float*)d_in[0];   // 4096*28*28
    const float* params = (const float*)d_in[1];   // 2*4*3
    float* out = (float*)d_out;                    // 4096*784

    const int npatch = 4096 * 196;                 // 802816, divisible by 256
    quanv_kernel<<<npatch / 256, 256, 0, stream>>>(x, params, out);
}